// Round 6
// baseline (5696.202 us; speedup 1.0000x reference)
//
#include <hip/hip_runtime.h>
#include <cstdint>
#include <cstddef>

typedef _Float16 half8  __attribute__((ext_vector_type(8)));
typedef _Float16 half2v __attribute__((ext_vector_type(2)));
typedef float    floatx4 __attribute__((ext_vector_type(4)));

#define B_  64
#define T_  512
#define D_  512
#define H_  512
#define NG  2048   // 4*H

#if defined(__has_builtin)
#if __has_builtin(__builtin_amdgcn_fdot2)
#define HAVE_FDOT2 1
#endif
#endif

static __device__ __forceinline__ float fdot2_acc(half2v a, half2v b, float c) {
#ifdef HAVE_FDOT2
  return __builtin_amdgcn_fdot2(a, b, c, false);
#else
  return fmaf((float)a[0], (float)b[0], fmaf((float)a[1], (float)b[1], c));
#endif
}
static __device__ __forceinline__ half2v h2(half8 v, int i) {
  half2v r; r[0] = v[2*i]; r[1] = v[2*i+1]; return r;
}
static __device__ __forceinline__ float fast_sigmoid(float x) {
  return 1.0f / (1.0f + __expf(-x));
}
static __device__ __forceinline__ float fast_tanh(float x) {
  x = fminf(15.0f, fmaxf(-15.0f, x));
  float e = __expf(2.0f * x);
  return (e - 1.0f) / (e + 1.0f);
}

// LDS-only barrier: drains lgkmcnt (DS) but NOT vmcnt — global loads/stores
// stay in flight across it. __syncthreads would force vmcnt(0) [m97 asm].
#define LDS_BARRIER() do {                                   \
    asm volatile("s_waitcnt lgkmcnt(0)" ::: "memory");       \
    __builtin_amdgcn_s_barrier();                            \
  } while (0)

// ---------------------------------------------------------------------------
// Kernel 1: input projections (unchanged — measured ~0.17 ms)
// ---------------------------------------------------------------------------
__global__ __launch_bounds__(256) void proj_kernel(
    const float* __restrict__ x,
    const float* __restrict__ Wc, const float* __restrict__ Wi,
    const float* __restrict__ Wf, const float* __restrict__ Wo,
    const float* __restrict__ bc, const float* __restrict__ bi,
    const float* __restrict__ bf2, const float* __restrict__ bo,
    _Float16* __restrict__ XG)
{
  const int tiles_n = NG / 64;
  int tM = blockIdx.x / tiles_n;
  int tN = blockIdx.x % tiles_n;
  int r0 = tM * 64;
  int t0 = r0 >> 6;
  int n0 = tN * 64;
  int g  = n0 >> 9;
  const float* W    = (g==0) ? Wc : (g==1) ? Wi : (g==2) ? Wf : Wo;
  const float* bias = (g==0) ? bc : (g==1) ? bi : (g==2) ? bf2 : bo;
  int j0 = n0 & (H_-1);

  __shared__ _Float16 Al[64*40];
  __shared__ _Float16 Bl[64*40];

  int tid  = threadIdx.x;
  int wave = tid >> 6;
  int lane = tid & 63;

  floatx4 acc[4] = {};

  int arow = tid >> 2;
  int ak0  = (tid & 3) * 8;
  const float* xsrc = x + ((size_t)arow * T_ + t0) * D_;

  int bcol = tid & 63;
  int bk0  = (tid >> 6) * 8;

  for (int k0 = 0; k0 < D_; k0 += 32) {
    half8 av;
    #pragma unroll
    for (int i = 0; i < 8; ++i) av[i] = (_Float16)xsrc[k0 + ak0 + i];
    *(half8*)&Al[arow*40 + ak0] = av;

    half8 bv;
    #pragma unroll
    for (int i = 0; i < 8; ++i)
      bv[i] = (_Float16)W[(size_t)(k0 + bk0 + i) * H_ + j0 + bcol];
    *(half8*)&Bl[bcol*40 + bk0] = bv;

    __syncthreads();

    half8 afrag = *(half8*)&Al[(wave*16 + (lane & 15))*40 + (lane >> 4)*8];
    #pragma unroll
    for (int ct = 0; ct < 4; ++ct) {
      half8 bfrag = *(half8*)&Bl[(ct*16 + (lane & 15))*40 + (lane >> 4)*8];
      acc[ct] = __builtin_amdgcn_mfma_f32_16x16x32_f16(afrag, bfrag, acc[ct], 0, 0, 0);
    }
    __syncthreads();
  }

  #pragma unroll
  for (int ct = 0; ct < 4; ++ct) {
    int col = n0 + ct*16 + (lane & 15);
    float bvs = bias[col & (H_-1)];
    #pragma unroll
    for (int i = 0; i < 4; ++i) {
      int row = r0 + wave*16 + (lane >> 4)*4 + i;
      XG[(size_t)row * NG + col] = (_Float16)(acc[ct][i] + bvs);
    }
  }
}

// ---------------------------------------------------------------------------
// Kernel 2: persistent scan, v5.
//   - tagged-word handoff + sweep-parallel poll (unchanged from v4)
//   - LDS-only barriers (no vmcnt drain per step)
//   - XG prefetched one step ahead (HBM latency hidden under step t's work)
//   - out[] stores batched x8 via LDS obuf, flushed off the critical path
// ---------------------------------------------------------------------------
#define SH 520   // f16 row stride

__global__ __launch_bounds__(256) void scan_kernel(
    const _Float16* __restrict__ XG,
    const float* __restrict__ Uc, const float* __restrict__ Ui,
    const float* __restrict__ Uf, const float* __restrict__ Uo,
    float* __restrict__ out, unsigned* __restrict__ h_buf)
{
  extern __shared__ _Float16 lds[];
  _Float16* U_lds = lds;                        // 64 rows x SH (row = g*16+jj)
  _Float16* h_lds = lds + 64*SH;                // 8 rows x SH
  float*  act_buf = (float*)(lds + 72*SH);      // 256 f32: activated i,o
  float*  obuf    = act_buf + 256;              // 8 x 128 f32: out batch

  int tid = threadIdx.x;
  int grp = blockIdx.x & 7;
  int member = blockIdx.x >> 3;
  int j0 = member * 16;

  { // one-time: stage U columns transposed into LDS, f32 -> f16
    int jj = tid & 15;
    int kk = tid >> 4;
    #pragma unroll
    for (int g = 0; g < 4; ++g) {
      const float* U = (g==0) ? Uc : (g==1) ? Ui : (g==2) ? Uf : Uo;
      _Float16* dst = &U_lds[(g*16 + jj)*SH];
      for (int k = kk; k < H_; k += 16)
        dst[k] = (_Float16)U[(size_t)k * H_ + j0 + jj];
    }
  }
  __syncthreads();

  int b   = tid & 7;
  int jj  = (tid >> 3) & 15;
  int gh  = tid >> 7;             // wave-uniform: 0 -> (a,f); 1 -> (i,o)
  int bglob = grp*8 + b;
  int j = j0 + jj;

  const half8* Ur0 = (const half8*)&U_lds[((gh    )*16 + jj)*SH];
  const half8* Ur1 = (const half8*)&U_lds[((gh + 2)*16 + jj)*SH];
  const half8* Hr  = (const half8*)&h_lds[b*SH];

  // staging geometry: thread covers 16 consecutive cols of one batch row
  int srow = tid >> 5;            // 0..7
  int sc0  = (tid & 31) * 16;

  // flush geometry: thread covers 4 consecutive obuf entries of one q-slot
  int fq  = tid >> 5;             // q slot 0..7
  int fl0 = (tid & 31) * 4;       // lane128 base

  float c_reg = 0.0f;

  // preload XG for t=0
  float xg0, xg1;
  {
    size_t xb = (size_t)bglob * NG;
    xg0 = (float)XG[xb + (size_t)gh*H_ + j];
    xg1 = (float)XG[xb + (size_t)(gh + 2)*H_ + j];
  }

  for (int t = 0; t < T_; ++t) {
    // ---- stage h^t: sweep-parallel tagged poll, then LDS write ----
    {
      const unsigned long long* src8 = (const unsigned long long*)
          &h_buf[(size_t)(t & 1)*(B_*H_) + (size_t)(grp*8 + srow)*H_ + sc0];
      unsigned long long want2 = (unsigned long long)((unsigned)t & 0xFFFFu);
      want2 |= want2 << 32;
      unsigned long long w8[8];
      for (;;) {
        #pragma unroll
        for (int q = 0; q < 8; ++q)
          w8[q] = __hip_atomic_load(&src8[q], __ATOMIC_RELAXED,
                                    __HIP_MEMORY_SCOPE_AGENT);
        unsigned long long diff = 0;
        #pragma unroll
        for (int q = 0; q < 8; ++q)
          diff |= (w8[q] ^ want2) & 0x0000FFFF0000FFFFull;
        if (diff == 0) break;
      }
      half8 hv0, hv1;
      #pragma unroll
      for (int q = 0; q < 4; ++q) {
        hv0[2*q]   = __builtin_bit_cast(_Float16, (unsigned short)(w8[q]   >> 16));
        hv0[2*q+1] = __builtin_bit_cast(_Float16, (unsigned short)(w8[q]   >> 48));
        hv1[2*q]   = __builtin_bit_cast(_Float16, (unsigned short)(w8[4+q] >> 16));
        hv1[2*q+1] = __builtin_bit_cast(_Float16, (unsigned short)(w8[4+q] >> 48));
      }
      *(half8*)&h_lds[srow*SH + sc0]     = hv0;
      *(half8*)&h_lds[srow*SH + sc0 + 8] = hv1;
    }
    LDS_BARRIER();   // staged h visible (LDS-only drain)

    // ---- flush the previous 8 steps' h to out (off critical path) ----
    if ((t & 7) == 0 && t > 0) {
      #pragma unroll
      for (int i = 0; i < 4; ++i) {
        int l = fl0 + i;                       // lane128
        float v = obuf[fq*128 + l];
        out[((size_t)(grp*8 + (l & 7)) * T_ + (t - 8 + fq)) * H_ + j0 + (l >> 3)] = v;
      }
    }

    // ---- prefetch XG for t+1 (in flight across dots + finish + next poll) ----
    float xgn0 = 0.f, xgn1 = 0.f;
    if (t + 1 < T_) {
      size_t xbn = ((size_t)(t + 1) * B_ + bglob) * NG;
      xgn0 = (float)XG[xbn + (size_t)gh*H_ + j];
      xgn1 = (float)XG[xbn + (size_t)(gh + 2)*H_ + j];
    }

    // ---- dots ----
    float acc0 = 0.f, acc1 = 0.f;
    #pragma unroll 4
    for (int k8 = 0; k8 < H_/8; ++k8) {
      half8 hv = Hr[k8];
      half8 u0 = Ur0[k8];
      half8 u1 = Ur1[k8];
      #pragma unroll
      for (int i = 0; i < 4; ++i) {
        acc0 = fdot2_acc(h2(hv,i), h2(u0,i), acc0);
        acc1 = fdot2_acc(h2(hv,i), h2(u1,i), acc1);
      }
    }
    float pre0 = acc0 + xg0;     // gh0: a-gate   gh1: i-gate
    float pre1 = acc1 + xg1;     // gh0: f-gate   gh1: o-gate

    float act0 = (gh == 0) ? fast_tanh(pre0) : fast_sigmoid(pre0);
    float act1 = fast_sigmoid(pre1);

    if (gh == 1) {
      act_buf[(b*16 + jj)*2    ] = act0;   // sigmoid(i)
      act_buf[(b*16 + jj)*2 + 1] = act1;   // sigmoid(o)
    }
    LDS_BARRIER();   // act_buf visible; all h_lds reads done

    if (gh == 0) {
      float iv = act_buf[(b*16 + jj)*2];
      float ov = act_buf[(b*16 + jj)*2 + 1];
      float cn = fmaf(act1, c_reg, iv * act0);   // f*c + i*a
      c_reg = cn;
      float hval = ov * fast_tanh(cn);
      if (t + 1 < T_) {   // publish FIRST (critical path)
        unsigned wv = ((unsigned)__builtin_bit_cast(unsigned short, (_Float16)hval) << 16)
                    | ((unsigned)(t + 1) & 0xFFFFu);
        __hip_atomic_store(&h_buf[(size_t)((t + 1) & 1)*(B_*H_) + (size_t)bglob*H_ + j],
                           wv, __ATOMIC_RELAXED, __HIP_MEMORY_SCOPE_AGENT);
      }
      obuf[(t & 7)*128 + tid] = hval;   // batched out (LDS, cheap)
    }

    xg0 = xgn0;
    xg1 = xgn1;
  }

  // tail flush: steps T-8..T-1
  LDS_BARRIER();
  {
    #pragma unroll
    for (int i = 0; i < 4; ++i) {
      int l = fl0 + i;
      float v = obuf[fq*128 + l];
      out[((size_t)(grp*8 + (l & 7)) * T_ + (T_ - 8 + fq)) * H_ + j0 + (l >> 3)] = v;
    }
  }
}

// ---------------------------------------------------------------------------
extern "C" void kernel_launch(void* const* d_in, const int* in_sizes, int n_in,
                              void* d_out, int out_size, void* d_ws, size_t ws_size,
                              hipStream_t stream)
{
  const float* x  = (const float*)d_in[0];
  const float* Wc = (const float*)d_in[1];
  const float* Wi = (const float*)d_in[2];
  const float* Wf = (const float*)d_in[3];
  const float* Wo = (const float*)d_in[4];
  const float* Uc = (const float*)d_in[5];
  const float* Ui = (const float*)d_in[6];
  const float* Uf = (const float*)d_in[7];
  const float* Uo = (const float*)d_in[8];
  const float* bc = (const float*)d_in[9];
  const float* bi = (const float*)d_in[10];
  const float* bf2= (const float*)d_in[11];
  const float* bo = (const float*)d_in[12];
  float* out = (float*)d_out;

  const size_t XG_BYTES = (size_t)T_ * B_ * NG * sizeof(_Float16);  // 128 MiB
  const size_t HB_BYTES = (size_t)2 * B_ * H_ * sizeof(unsigned);   // 256 KiB

  if (ws_size < XG_BYTES + HB_BYTES) return;

  _Float16* XG   = (_Float16*)d_ws;
  unsigned* hbuf = (unsigned*)((char*)d_ws + XG_BYTES);

  // tag 0 / h=0 initial state; also kills cross-replay tag aliasing
  (void)hipMemsetAsync(hbuf, 0, HB_BYTES, stream);

  proj_kernel<<<dim3((T_*B_/64) * (NG/64)), dim3(256), 0, stream>>>(
      x, Wc, Wi, Wf, Wo, bc, bi, bf2, bo, XG);

  // LDS: U 64*SH + h 8*SH halfs, act_buf 256 f32, obuf 1024 f32
  const int lds_bytes = 72*SH*2 + 256*4 + 1024*4;   // 80,000 B
  (void)hipFuncSetAttribute(reinterpret_cast<const void*>(scan_kernel),
                      hipFuncAttributeMaxDynamicSharedMemorySize, lds_bytes);
  scan_kernel<<<dim3(256), dim3(256), lds_bytes, stream>>>(
      XG, Uc, Ui, Uf, Uo, out, hbuf);
}

// Round 7
// 4534.361 us; speedup vs baseline: 1.2562x; 1.2562x over previous
//
#include <hip/hip_runtime.h>
#include <cstdint>
#include <cstddef>

typedef _Float16 half8  __attribute__((ext_vector_type(8)));
typedef _Float16 half2v __attribute__((ext_vector_type(2)));
typedef float    floatx4 __attribute__((ext_vector_type(4)));

#define B_  64
#define T_  512
#define D_  512
#define H_  512
#define NG  2048   // 4*H

#if defined(__has_builtin)
#if __has_builtin(__builtin_amdgcn_fdot2)
#define HAVE_FDOT2 1
#endif
#endif

static __device__ __forceinline__ float fdot2_acc(half2v a, half2v b, float c) {
#ifdef HAVE_FDOT2
  return __builtin_amdgcn_fdot2(a, b, c, false);
#else
  return fmaf((float)a[0], (float)b[0], fmaf((float)a[1], (float)b[1], c));
#endif
}
static __device__ __forceinline__ half2v h2(half8 v, int i) {
  half2v r; r[0] = v[2*i]; r[1] = v[2*i+1]; return r;
}
static __device__ __forceinline__ float fast_sigmoid(float x) {
  return 1.0f / (1.0f + __expf(-x));
}
static __device__ __forceinline__ float fast_tanh(float x) {
  x = fminf(15.0f, fmaxf(-15.0f, x));
  float e = __expf(2.0f * x);
  return (e - 1.0f) / (e + 1.0f);
}

// LDS-only barrier: drains lgkmcnt but NOT vmcnt.
#define LDS_BARRIER() do {                                   \
    asm volatile("s_waitcnt lgkmcnt(0)" ::: "memory");       \
    __builtin_amdgcn_s_barrier();                            \
  } while (0)

// ---------------------------------------------------------------------------
// Kernel 1: input projections (unchanged — measured ~0.17 ms)
// ---------------------------------------------------------------------------
__global__ __launch_bounds__(256) void proj_kernel(
    const float* __restrict__ x,
    const float* __restrict__ Wc, const float* __restrict__ Wi,
    const float* __restrict__ Wf, const float* __restrict__ Wo,
    const float* __restrict__ bc, const float* __restrict__ bi,
    const float* __restrict__ bf2, const float* __restrict__ bo,
    _Float16* __restrict__ XG)
{
  const int tiles_n = NG / 64;
  int tM = blockIdx.x / tiles_n;
  int tN = blockIdx.x % tiles_n;
  int r0 = tM * 64;
  int t0 = r0 >> 6;
  int n0 = tN * 64;
  int g  = n0 >> 9;
  const float* W    = (g==0) ? Wc : (g==1) ? Wi : (g==2) ? Wf : Wo;
  const float* bias = (g==0) ? bc : (g==1) ? bi : (g==2) ? bf2 : bo;
  int j0 = n0 & (H_-1);

  __shared__ _Float16 Al[64*40];
  __shared__ _Float16 Bl[64*40];

  int tid  = threadIdx.x;
  int wave = tid >> 6;
  int lane = tid & 63;

  floatx4 acc[4] = {};

  int arow = tid >> 2;
  int ak0  = (tid & 3) * 8;
  const float* xsrc = x + ((size_t)arow * T_ + t0) * D_;

  int bcol = tid & 63;
  int bk0  = (tid >> 6) * 8;

  for (int k0 = 0; k0 < D_; k0 += 32) {
    half8 av;
    #pragma unroll
    for (int i = 0; i < 8; ++i) av[i] = (_Float16)xsrc[k0 + ak0 + i];
    *(half8*)&Al[arow*40 + ak0] = av;

    half8 bv;
    #pragma unroll
    for (int i = 0; i < 8; ++i)
      bv[i] = (_Float16)W[(size_t)(k0 + bk0 + i) * H_ + j0 + bcol];
    *(half8*)&Bl[bcol*40 + bk0] = bv;

    __syncthreads();

    half8 afrag = *(half8*)&Al[(wave*16 + (lane & 15))*40 + (lane >> 4)*8];
    #pragma unroll
    for (int ct = 0; ct < 4; ++ct) {
      half8 bfrag = *(half8*)&Bl[(ct*16 + (lane & 15))*40 + (lane >> 4)*8];
      acc[ct] = __builtin_amdgcn_mfma_f32_16x16x32_f16(afrag, bfrag, acc[ct], 0, 0, 0);
    }
    __syncthreads();
  }

  #pragma unroll
  for (int ct = 0; ct < 4; ++ct) {
    int col = n0 + ct*16 + (lane & 15);
    float bvs = bias[col & (H_-1)];
    #pragma unroll
    for (int i = 0; i < 4; ++i) {
      int row = r0 + wave*16 + (lane >> 4)*4 + i;
      XG[(size_t)row * NG + col] = (_Float16)(acc[ct][i] + bvs);
    }
  }
}

// ---------------------------------------------------------------------------
// Kernel 2: persistent scan, v6 — epoch barrier + bulk payload read.
//   Data: dbuf[parity][grp][member*128 + b*16 + jj] = (f16<<16)|step_tag.
//   Producer: contiguous 256B store per wave -> vmcnt(0) -> epoch word.
//   Consumer: wave 2 polls 64 epoch words (2 lines, coalesced), barrier
//   releases WG, ONE bulk read of payload (tags verified; retry fallback).
// ---------------------------------------------------------------------------
#define SH 520   // f16 row stride

__global__ __launch_bounds__(256) void scan_kernel(
    const _Float16* __restrict__ XG,
    const float* __restrict__ Uc, const float* __restrict__ Ui,
    const float* __restrict__ Uf, const float* __restrict__ Uo,
    float* __restrict__ out,
    unsigned* __restrict__ dbuf, unsigned* __restrict__ epoch)
{
  extern __shared__ _Float16 lds[];
  _Float16* U_lds = lds;                       // 64 rows x SH (row = g*16+jj)
  _Float16* h_lds = lds + 64*SH;               // 8 rows x SH
  float*  act_buf = (float*)(lds + 72*SH);     // 128*2 f32 activated i,o

  int tid = threadIdx.x;
  int grp = blockIdx.x & 7;
  int member = blockIdx.x >> 3;
  int j0 = member * 16;

  { // one-time: stage U columns transposed into LDS, f32 -> f16
    int jj = tid & 15;
    int kk = tid >> 4;
    #pragma unroll
    for (int g = 0; g < 4; ++g) {
      const float* U = (g==0) ? Uc : (g==1) ? Ui : (g==2) ? Uf : Uo;
      _Float16* dst = &U_lds[(g*16 + jj)*SH];
      for (int k = kk; k < H_; k += 16)
        dst[k] = (_Float16)U[(size_t)k * H_ + j0 + jj];
    }
  }
  __syncthreads();

  // thread mapping: local = tid&127; b = local>>4 (0..7); jj = local&15.
  //   -> gh0 wave 0 covers data words 0..63 (contiguous), wave 1: 64..127.
  int gh    = tid >> 7;
  int local = tid & 127;
  int b     = local >> 4;
  int jj    = local & 15;
  int bglob = grp*8 + b;
  int j = j0 + jj;

  const half8* Ur0 = (const half8*)&U_lds[((gh    )*16 + jj)*SH];
  const half8* Ur1 = (const half8*)&U_lds[((gh + 2)*16 + jj)*SH];
  const half8* Hr  = (const half8*)&h_lds[b*SH];

  // bulk-read geometry: thread imports member (tid&31), batch row (tid>>5)
  int rmem  = tid & 31;
  int srow  = tid >> 5;

  unsigned* grp_epoch = &epoch[grp*64];

  float c_reg = 0.0f;

  // preload XG for t=0
  float xg0, xg1;
  {
    size_t xb = (size_t)bglob * NG;
    xg0 = (float)XG[xb + (size_t)gh*H_ + j];
    xg1 = (float)XG[xb + (size_t)(gh + 2)*H_ + j];
  }

  for (int t = 0; t < T_; ++t) {
    // ---- phase 1: wave 2 polls the 64 epoch words (2 cachelines) ----
    if ((tid >> 6) == 2) {
      unsigned want = (unsigned)t;
      for (;;) {
        unsigned e = __hip_atomic_load(&grp_epoch[tid & 63], __ATOMIC_RELAXED,
                                       __HIP_MEMORY_SCOPE_AGENT);
        if (__all((int)(e >= want))) break;
      }
    }
    LDS_BARRIER();   // epoch pass gates the whole WG

    // ---- phase 2: ONE bulk read of payload; verify tags; stage to LDS ----
    {
      const unsigned long long* src8 = (const unsigned long long*)
          &dbuf[((size_t)(t & 1)*8 + grp)*4096 + rmem*128 + srow*16];
      unsigned long long want2 = (unsigned long long)((unsigned)t & 0xFFFFu);
      want2 |= want2 << 32;
      unsigned long long w8[8];
      #pragma unroll
      for (int q = 0; q < 8; ++q)
        w8[q] = __hip_atomic_load(&src8[q], __ATOMIC_RELAXED,
                                  __HIP_MEMORY_SCOPE_AGENT);
      unsigned long long diff;
      do {
        diff = 0;
        #pragma unroll
        for (int q = 0; q < 8; ++q)
          diff |= (w8[q] ^ want2) & 0x0000FFFF0000FFFFull;
        if (diff) {   // rare: epoch ack beat data visibility — re-read
          #pragma unroll
          for (int q = 0; q < 8; ++q)
            w8[q] = __hip_atomic_load(&src8[q], __ATOMIC_RELAXED,
                                      __HIP_MEMORY_SCOPE_AGENT);
        }
      } while (diff);
      half8 hv0, hv1;
      #pragma unroll
      for (int q = 0; q < 4; ++q) {
        hv0[2*q]   = __builtin_bit_cast(_Float16, (unsigned short)(w8[q]   >> 16));
        hv0[2*q+1] = __builtin_bit_cast(_Float16, (unsigned short)(w8[q]   >> 48));
        hv1[2*q]   = __builtin_bit_cast(_Float16, (unsigned short)(w8[4+q] >> 16));
        hv1[2*q+1] = __builtin_bit_cast(_Float16, (unsigned short)(w8[4+q] >> 48));
      }
      *(half8*)&h_lds[srow*SH + rmem*16]     = hv0;
      *(half8*)&h_lds[srow*SH + rmem*16 + 8] = hv1;
    }
    LDS_BARRIER();   // staged h visible

    // ---- phase 3: dots ----
    float acc0 = 0.f, acc1 = 0.f;
    #pragma unroll 4
    for (int k8 = 0; k8 < H_/8; ++k8) {
      half8 hv = Hr[k8];
      half8 u0 = Ur0[k8];
      half8 u1 = Ur1[k8];
      #pragma unroll
      for (int i = 0; i < 4; ++i) {
        acc0 = fdot2_acc(h2(hv,i), h2(u0,i), acc0);
        acc1 = fdot2_acc(h2(hv,i), h2(u1,i), acc1);
      }
    }
    float pre0 = acc0 + xg0;     // gh0: a-gate   gh1: i-gate
    float pre1 = acc1 + xg1;     // gh0: f-gate   gh1: o-gate

    float act0 = (gh == 0) ? fast_tanh(pre0) : fast_sigmoid(pre0);
    float act1 = fast_sigmoid(pre1);

    if (gh == 1) {
      act_buf[local*2    ] = act0;   // sigmoid(i)
      act_buf[local*2 + 1] = act1;   // sigmoid(o)
    }
    LDS_BARRIER();   // act_buf visible; h_lds reads done

    // ---- phase 4: finish + publish (gh0 only) ----
    if (gh == 0) {
      float iv = act_buf[local*2];
      float ov = act_buf[local*2 + 1];
      float cn = fmaf(act1, c_reg, iv * act0);   // f*c + i*a
      c_reg = cn;
      float hval = ov * fast_tanh(cn);
      if (t + 1 < T_) {
        unsigned wv = ((unsigned)__builtin_bit_cast(unsigned short, (_Float16)hval) << 16)
                    | ((unsigned)(t + 1) & 0xFFFFu);
        __hip_atomic_store(&dbuf[((size_t)((t + 1) & 1)*8 + grp)*4096
                                 + member*128 + local],
                           wv, __ATOMIC_RELAXED, __HIP_MEMORY_SCOPE_AGENT);
        asm volatile("s_waitcnt vmcnt(0)" ::: "memory");   // data store acked
        if ((tid & 63) == 0)   // lane 0 of each gh0 wave
          __hip_atomic_store(&grp_epoch[member*2 + (tid >> 6)], (unsigned)(t + 1),
                             __ATOMIC_RELAXED, __HIP_MEMORY_SCOPE_AGENT);
      }
      out[((size_t)bglob * T_ + t) * H_ + j] = hval;   // off critical path
    }

    // ---- phase 5: prefetch XG for t+1 ----
    if (t + 1 < T_) {
      size_t xbn = ((size_t)(t + 1) * B_ + bglob) * NG;
      xg0 = (float)XG[xbn + (size_t)gh*H_ + j];
      xg1 = (float)XG[xbn + (size_t)(gh + 2)*H_ + j];
    }
  }
}

// ---------------------------------------------------------------------------
extern "C" void kernel_launch(void* const* d_in, const int* in_sizes, int n_in,
                              void* d_out, int out_size, void* d_ws, size_t ws_size,
                              hipStream_t stream)
{
  const float* x  = (const float*)d_in[0];
  const float* Wc = (const float*)d_in[1];
  const float* Wi = (const float*)d_in[2];
  const float* Wf = (const float*)d_in[3];
  const float* Wo = (const float*)d_in[4];
  const float* Uc = (const float*)d_in[5];
  const float* Ui = (const float*)d_in[6];
  const float* Uf = (const float*)d_in[7];
  const float* Uo = (const float*)d_in[8];
  const float* bc = (const float*)d_in[9];
  const float* bi = (const float*)d_in[10];
  const float* bf2= (const float*)d_in[11];
  const float* bo = (const float*)d_in[12];
  float* out = (float*)d_out;

  const size_t XG_BYTES = (size_t)T_ * B_ * NG * sizeof(_Float16);  // 128 MiB
  const size_t DB_BYTES = (size_t)2 * 8 * 4096 * sizeof(unsigned);  // 256 KiB
  const size_t EP_BYTES = 8 * 64 * sizeof(unsigned);                // 2 KiB

  if (ws_size < XG_BYTES + DB_BYTES + EP_BYTES) return;

  _Float16* XG    = (_Float16*)d_ws;
  unsigned* dbuf  = (unsigned*)((char*)d_ws + XG_BYTES);
  unsigned* epoch = (unsigned*)((char*)d_ws + XG_BYTES + DB_BYTES);

  // zero: data tag 0 == h^0 = 0; epoch 0 == "step-0 data ready"
  (void)hipMemsetAsync(dbuf, 0, DB_BYTES + EP_BYTES, stream);

  proj_kernel<<<dim3((T_*B_/64) * (NG/64)), dim3(256), 0, stream>>>(
      x, Wc, Wi, Wf, Wo, bc, bi, bf2, bo, XG);

  const int lds_bytes = 72*SH*2 + 256*4;   // 75,904 B
  (void)hipFuncSetAttribute(reinterpret_cast<const void*>(scan_kernel),
                      hipFuncAttributeMaxDynamicSharedMemorySize, lds_bytes);
  scan_kernel<<<dim3(256), dim3(256), lds_bytes, stream>>>(
      XG, Uc, Ui, Uf, Uo, out, dbuf, epoch);
}

// Round 9
// 2372.432 us; speedup vs baseline: 2.4010x; 1.9113x over previous
//
#include <hip/hip_runtime.h>
#include <cstdint>
#include <cstddef>

typedef _Float16 half8  __attribute__((ext_vector_type(8)));
typedef _Float16 half2v __attribute__((ext_vector_type(2)));
typedef float    floatx4 __attribute__((ext_vector_type(4)));

#define B_  64
#define T_  512
#define D_  512
#define H_  512
#define NG  2048   // 4*H

#if defined(__has_builtin)
#if __has_builtin(__builtin_amdgcn_fdot2)
#define HAVE_FDOT2 1
#endif
#endif

static __device__ __forceinline__ float fdot2_acc(half2v a, half2v b, float c) {
#ifdef HAVE_FDOT2
  return __builtin_amdgcn_fdot2(a, b, c, false);
#else
  return fmaf((float)a[0], (float)b[0], fmaf((float)a[1], (float)b[1], c));
#endif
}
static __device__ __forceinline__ half2v h2(half8 v, int i) {
  half2v r; r[0] = v[2*i]; r[1] = v[2*i+1]; return r;
}
static __device__ __forceinline__ float fast_sigmoid(float x) {
  return 1.0f / (1.0f + __expf(-x));
}
static __device__ __forceinline__ float fast_tanh(float x) {
  x = fminf(15.0f, fmaxf(-15.0f, x));
  float e = __expf(2.0f * x);
  return (e - 1.0f) / (e + 1.0f);
}

// LDS-only barrier: drains lgkmcnt but NOT vmcnt (global ops stay in flight).
#define LDS_BARRIER() do {                                   \
    asm volatile("s_waitcnt lgkmcnt(0)" ::: "memory");       \
    __builtin_amdgcn_s_barrier();                            \
  } while (0)

// ---------------------------------------------------------------------------
// Kernel 1: input projections (unchanged — measured ~0.17 ms)
// ---------------------------------------------------------------------------
__global__ __launch_bounds__(256) void proj_kernel(
    const float* __restrict__ x,
    const float* __restrict__ Wc, const float* __restrict__ Wi,
    const float* __restrict__ Wf, const float* __restrict__ Wo,
    const float* __restrict__ bc, const float* __restrict__ bi,
    const float* __restrict__ bf2, const float* __restrict__ bo,
    _Float16* __restrict__ XG)
{
  const int tiles_n = NG / 64;
  int tM = blockIdx.x / tiles_n;
  int tN = blockIdx.x % tiles_n;
  int r0 = tM * 64;
  int t0 = r0 >> 6;
  int n0 = tN * 64;
  int g  = n0 >> 9;
  const float* W    = (g==0) ? Wc : (g==1) ? Wi : (g==2) ? Wf : Wo;
  const float* bias = (g==0) ? bc : (g==1) ? bi : (g==2) ? bf2 : bo;
  int j0 = n0 & (H_-1);

  __shared__ _Float16 Al[64*40];
  __shared__ _Float16 Bl[64*40];

  int tid  = threadIdx.x;
  int wave = tid >> 6;
  int lane = tid & 63;

  floatx4 acc[4] = {};

  int arow = tid >> 2;
  int ak0  = (tid & 3) * 8;
  const float* xsrc = x + ((size_t)arow * T_ + t0) * D_;

  int bcol = tid & 63;
  int bk0  = (tid >> 6) * 8;

  for (int k0 = 0; k0 < D_; k0 += 32) {
    half8 av;
    #pragma unroll
    for (int i = 0; i < 8; ++i) av[i] = (_Float16)xsrc[k0 + ak0 + i];
    *(half8*)&Al[arow*40 + ak0] = av;

    half8 bv;
    #pragma unroll
    for (int i = 0; i < 8; ++i)
      bv[i] = (_Float16)W[(size_t)(k0 + bk0 + i) * H_ + j0 + bcol];
    *(half8*)&Bl[bcol*40 + bk0] = bv;

    __syncthreads();

    half8 afrag = *(half8*)&Al[(wave*16 + (lane & 15))*40 + (lane >> 4)*8];
    #pragma unroll
    for (int ct = 0; ct < 4; ++ct) {
      half8 bfrag = *(half8*)&Bl[(ct*16 + (lane & 15))*40 + (lane >> 4)*8];
      acc[ct] = __builtin_amdgcn_mfma_f32_16x16x32_f16(afrag, bfrag, acc[ct], 0, 0, 0);
    }
    __syncthreads();
  }

  #pragma unroll
  for (int ct = 0; ct < 4; ++ct) {
    int col = n0 + ct*16 + (lane & 15);
    float bvs = bias[col & (H_-1)];
    #pragma unroll
    for (int i = 0; i < 4; ++i) {
      int row = r0 + wave*16 + (lane >> 4)*4 + i;
      XG[(size_t)row * NG + col] = (_Float16)(acc[ct][i] + bvs);
    }
  }
}

// ---------------------------------------------------------------------------
// Kernel 2: persistent scan, v9 — direct tagged-data poll, all compiler-
//   emitted agent atomics (R4-R7's verified fabric; zero inline-asm loads).
//   Word = (f16 h << 16) | step tag. Masked retry re-reads only lagging
//   members' words; s_sleep backoff prevents R5's poll flooding. No fences,
//   no acks, no epoch. Double-buffer by t&1 (transitive-dependency safe).
// ---------------------------------------------------------------------------
#define SH 520   // f16 row stride

__global__ __launch_bounds__(256) void scan_kernel(
    const _Float16* __restrict__ XG,
    const float* __restrict__ Uc, const float* __restrict__ Ui,
    const float* __restrict__ Uf, const float* __restrict__ Uo,
    float* __restrict__ out, unsigned* __restrict__ dbuf)
{
  extern __shared__ _Float16 lds[];
  _Float16* U_lds = lds;                       // 64 rows x SH (row = g*16+jj)
  _Float16* h_lds = lds + 64*SH;               // 8 rows x SH
  float*  act_buf = (float*)(lds + 72*SH);     // 128*2 f32 activated i,o

  int tid = threadIdx.x;
  int grp = blockIdx.x & 7;
  int member = blockIdx.x >> 3;
  int j0 = member * 16;

  { // one-time: stage U columns transposed into LDS, f32 -> f16
    int jj = tid & 15;
    int kk = tid >> 4;
    #pragma unroll
    for (int g = 0; g < 4; ++g) {
      const float* U = (g==0) ? Uc : (g==1) ? Ui : (g==2) ? Uf : Uo;
      _Float16* dst = &U_lds[(g*16 + jj)*SH];
      for (int k = kk; k < H_; k += 16)
        dst[k] = (_Float16)U[(size_t)k * H_ + j0 + jj];
    }
  }
  __syncthreads();

  // compute mapping: local = b*16+jj within this member's 128-word block
  int gh    = tid >> 7;
  int local = tid & 127;
  int b     = local >> 4;
  int jj    = local & 15;
  int bglob = grp*8 + b;
  int j = j0 + jj;

  const half8* Ur0 = (const half8*)&U_lds[((gh    )*16 + jj)*SH];
  const half8* Ur1 = (const half8*)&U_lds[((gh + 2)*16 + jj)*SH];
  const half8* Hr  = (const half8*)&h_lds[b*SH];

  // consumer geometry: thread reads words [tid*16, tid*16+16) of the group
  // block -> all 16 words belong to member (tid>>3), batch row (tid&7)
  int cb  = tid & 7;
  int cj0 = (tid >> 3) * 16;

  float c_reg = 0.0f;

  // preload XG for t=0
  float xg0, xg1;
  {
    size_t xb = (size_t)bglob * NG;
    xg0 = (float)XG[xb + (size_t)gh*H_ + j];
    xg1 = (float)XG[xb + (size_t)(gh + 2)*H_ + j];
  }

  for (int t = 0; t < T_; ++t) {
    // ---- stage h^t: speculative bulk read + masked retry (agent atomics) ----
    {
      const unsigned long long* src8 = (const unsigned long long*)dbuf
          + ((unsigned)(t & 1))*16384u + (unsigned)grp*2048u + (unsigned)tid*8u;
      unsigned long long want2 = (unsigned long long)((unsigned)t & 0xFFFFu);
      want2 |= want2 << 32;
      unsigned long long w8[8];
      unsigned pend = 0xFFu;
      for (;;) {
        #pragma unroll
        for (int q = 0; q < 8; ++q)
          if (pend & (1u << q))
            w8[q] = __hip_atomic_load(src8 + q, __ATOMIC_RELAXED,
                                      __HIP_MEMORY_SCOPE_AGENT);
        unsigned npend = 0;
        #pragma unroll
        for (int q = 0; q < 8; ++q)
          if ((pend & (1u << q)) &&
              ((w8[q] ^ want2) & 0x0000FFFF0000FFFFull))
            npend |= 1u << q;
        if (!npend) break;
        pend = npend;
        __builtin_amdgcn_s_sleep(2);   // ~128 cyc backoff: no poll flooding
      }
      half8 hv0, hv1;
      #pragma unroll
      for (int q = 0; q < 4; ++q) {
        hv0[2*q]   = __builtin_bit_cast(_Float16, (unsigned short)(w8[q]   >> 16));
        hv0[2*q+1] = __builtin_bit_cast(_Float16, (unsigned short)(w8[q]   >> 48));
        hv1[2*q]   = __builtin_bit_cast(_Float16, (unsigned short)(w8[4+q] >> 16));
        hv1[2*q+1] = __builtin_bit_cast(_Float16, (unsigned short)(w8[4+q] >> 48));
      }
      *(half8*)&h_lds[cb*SH + cj0]     = hv0;
      *(half8*)&h_lds[cb*SH + cj0 + 8] = hv1;
    }
    LDS_BARRIER();   // staged h visible

    // ---- dots ----
    float acc0 = 0.f, acc1 = 0.f;
    #pragma unroll 4
    for (int k8 = 0; k8 < H_/8; ++k8) {
      half8 hv = Hr[k8];
      half8 u0 = Ur0[k8];
      half8 u1 = Ur1[k8];
      #pragma unroll
      for (int i = 0; i < 4; ++i) {
        acc0 = fdot2_acc(h2(hv,i), h2(u0,i), acc0);
        acc1 = fdot2_acc(h2(hv,i), h2(u1,i), acc1);
      }
    }
    float pre0 = acc0 + xg0;     // gh0: a-gate   gh1: i-gate
    float pre1 = acc1 + xg1;     // gh0: f-gate   gh1: o-gate

    float act0 = (gh == 0) ? fast_tanh(pre0) : fast_sigmoid(pre0);
    float act1 = fast_sigmoid(pre1);

    if (gh == 1) {
      act_buf[local*2    ] = act0;   // sigmoid(i)
      act_buf[local*2 + 1] = act1;   // sigmoid(o)
    }
    LDS_BARRIER();   // act_buf visible; h_lds reads done

    // ---- finish + publish (gh0 only) ----
    if (gh == 0) {
      float iv = act_buf[local*2];
      float ov = act_buf[local*2 + 1];
      float cn = fmaf(act1, c_reg, iv * act0);   // f*c + i*a
      c_reg = cn;
      float hval = ov * fast_tanh(cn);
      if (t + 1 < T_) {
        unsigned wv = ((unsigned)__builtin_bit_cast(unsigned short, (_Float16)hval) << 16)
                    | ((unsigned)(t + 1) & 0xFFFFu);
        unsigned idx = ((unsigned)((t + 1) & 1))*32768u + (unsigned)grp*4096u
                     + (unsigned)member*128u + (unsigned)local;
        __hip_atomic_store(&dbuf[idx], wv,
                           __ATOMIC_RELAXED, __HIP_MEMORY_SCOPE_AGENT);
      }
      out[((size_t)bglob * T_ + t) * H_ + j] = hval;   // in poll shadow
    }

    // ---- prefetch XG for t+1 (lands during next poll) ----
    if (t + 1 < T_) {
      size_t xbn = ((size_t)(t + 1) * B_ + bglob) * NG;
      xg0 = (float)XG[xbn + (size_t)gh*H_ + j];
      xg1 = (float)XG[xbn + (size_t)(gh + 2)*H_ + j];
    }
  }
}

// ---------------------------------------------------------------------------
extern "C" void kernel_launch(void* const* d_in, const int* in_sizes, int n_in,
                              void* d_out, int out_size, void* d_ws, size_t ws_size,
                              hipStream_t stream)
{
  const float* x  = (const float*)d_in[0];
  const float* Wc = (const float*)d_in[1];
  const float* Wi = (const float*)d_in[2];
  const float* Wf = (const float*)d_in[3];
  const float* Wo = (const float*)d_in[4];
  const float* Uc = (const float*)d_in[5];
  const float* Ui = (const float*)d_in[6];
  const float* Uf = (const float*)d_in[7];
  const float* Uo = (const float*)d_in[8];
  const float* bc = (const float*)d_in[9];
  const float* bi = (const float*)d_in[10];
  const float* bf2= (const float*)d_in[11];
  const float* bo = (const float*)d_in[12];
  float* out = (float*)d_out;

  const size_t XG_BYTES = (size_t)T_ * B_ * NG * sizeof(_Float16);  // 128 MiB
  const size_t DB_BYTES = (size_t)2 * 8 * 4096 * sizeof(unsigned);  // 256 KiB

  if (ws_size < XG_BYTES + DB_BYTES) return;

  _Float16* XG   = (_Float16*)d_ws;
  unsigned* dbuf = (unsigned*)((char*)d_ws + XG_BYTES);

  // tag 0 == "h^0 = 0 ready"; re-zeroed every launch (kills replay aliasing)
  (void)hipMemsetAsync(dbuf, 0, DB_BYTES, stream);

  proj_kernel<<<dim3((T_*B_/64) * (NG/64)), dim3(256), 0, stream>>>(
      x, Wc, Wi, Wf, Wo, bc, bi, bf2, bo, XG);

  const int lds_bytes = 72*SH*2 + 256*4;   // 75,904 B
  (void)hipFuncSetAttribute(reinterpret_cast<const void*>(scan_kernel),
                      hipFuncAttributeMaxDynamicSharedMemorySize, lds_bytes);
  scan_kernel<<<dim3(256), dim3(256), lds_bytes, stream>>>(
      XG, Uc, Ui, Uf, Uo, out, dbuf);
}